// Round 3
// baseline (189.357 us; speedup 1.0000x reference)
//
#include <hip/hip_runtime.h>
#include <hip/hip_bf16.h>
#include <stdint.h>
#include <stddef.h>

#define N_    4096
#define C_    1000
#define CP    1024
#define A_    64
#define KPACK 2080            // 64*65/2 packed upper-triangular
#define KCROSS (KPACK + 64)   // 2144 (end of live data)
#define KTOT  2176            // row length in fp8 bytes (17 x 128)
#define KSPLIT 1152           // z-slice boundary: 9 + 8 iterations of BK=128
#define MS    72              // LDS row stride for M staging (16B-aligned, 8-bank stride -> 4-way max)

typedef __bf16 bf16_8 __attribute__((ext_vector_type(8)));
typedef float  f32_4  __attribute__((ext_vector_type(4)));
typedef int    i32_4  __attribute__((ext_vector_type(4)));
typedef int    i32_8  __attribute__((ext_vector_type(8)));

__device__ __forceinline__ void gl2lds16(const void* g, void* l) {
  __builtin_amdgcn_global_load_lds(
      (const __attribute__((address_space(1))) void*)g,
      (__attribute__((address_space(3))) void*)l, 16, 0, 0);
}

// pack two floats -> two OCP e4m3 bytes (low 16 bits)
__device__ __forceinline__ uint16_t pk_fp8(float a, float b) {
  return (uint16_t)(__builtin_amdgcn_cvt_pk_fp8_f32(a, b, 0, false) & 0xffff);
}

// compile-time k -> (a<<8)|b table for packed upper-tri (a-major, b=a..63)
struct PairTab { uint16_t v[KPACK]; };
constexpr PairTab make_tab() {
  PairTab t{};
  int k = 0;
  for (int a = 0; a < 64; ++a)
    for (int b = a; b < 64; ++b) { t.v[k] = (uint16_t)((a << 8) | b); ++k; }
  return t;
}
__device__ constexpr PairTab PT = make_tab();

// ---------------- prep_all: blocks [0,1024) -> Bo + w2; [1024,5120) -> Aq + qn
__global__ __launch_bounds__(256) void prep_all(
    const float* __restrict__ W, const int* __restrict__ tgt,
    const float* __restrict__ CV, uint8_t* __restrict__ Bo,
    float* __restrict__ w2, uint8_t* __restrict__ Aq, float* __restrict__ qn,
    int* __restrict__ cnt) {
  __shared__ float Ms[64 * MS];
  __shared__ float up[4 * 64];
  __shared__ float wk[64];
  __shared__ float us[64];
  int t = threadIdx.x;

  if (blockIdx.x == 0 && t == 0) *cnt = 0;   // reset epilogue's last-block counter

  if (blockIdx.x < 1024) {
    int c = blockIdx.x;
    float* ws = Ms;
    if (t < 64) {
      float w = (c < C_) ? W[c * 64 + t] : 0.f;
      ws[t] = w;
      float s = w * w;
      for (int o = 32; o; o >>= 1) s += __shfl_down(s, o);
      if (t == 0 && c < C_) w2[c] = s;
    }
    __syncthreads();
    uint8_t* row = Bo + (size_t)c * KTOT;
    for (int p = t; p < KPACK / 2; p += 256) {
      int k = 2 * p;
      uint32_t pr = *(const uint32_t*)&PT.v[k];
      int b0 = pr & 255, a0 = (pr >> 8) & 255;
      int b1 = (pr >> 16) & 255, a1 = (pr >> 24) & 255;
      *(uint16_t*)(row + k) = pk_fp8(ws[a0] * ws[b0], ws[a1] * ws[b1]);
    }
    if (t < 32) *(uint16_t*)(row + KPACK + 2 * t) = pk_fp8(ws[2 * t], ws[2 * t + 1]);
    if (t >= 32 && t < 48) *(uint16_t*)(row + KCROSS + 2 * (t - 32)) = 0;
  } else {
    int n = blockIdx.x - 1024;
    int lbl = tgt[n];
    if (t < 64) wk[t] = W[lbl * 64 + t];
    const float4* M4 = (const float4*)(CV + (size_t)n * 4096);
    for (int j = 0; j < 4; ++j) {
      int i4 = t + j * 256;
      int r = i4 >> 4, c4 = (i4 & 15) << 2;
      *(float4*)&Ms[r * MS + c4] = M4[i4];
    }
    __syncthreads();
    {
      int a = t & 63, seg = t >> 6;
      float acc = 0.f;
      for (int b = seg * 16; b < seg * 16 + 16; ++b)
        acc += (Ms[a * MS + b] + Ms[b * MS + a]) * wk[b];
      up[seg * 64 + a] = acc;
    }
    __syncthreads();
    if (t < 64) {
      float u = up[t] + up[64 + t] + up[128 + t] + up[192 + t];
      us[t] = u;
      float p = wk[t] * u;
      for (int o = 32; o; o >>= 1) p += __shfl_down(p, o);
      if (t == 0) qn[n] = 0.5f * p;
    }
    __syncthreads();
    uint8_t* row = Aq + (size_t)n * KTOT;
    for (int p = t; p < KPACK / 2; p += 256) {
      int k = 2 * p;
      uint32_t pr = *(const uint32_t*)&PT.v[k];
      int b0 = pr & 255, a0 = (pr >> 8) & 255;
      int b1 = (pr >> 16) & 255, a1 = (pr >> 24) & 255;
      float v0 = (a0 == b0) ? Ms[a0 * MS + a0] : (Ms[a0 * MS + b0] + Ms[b0 * MS + a0]);
      float v1 = (a1 == b1) ? Ms[a1 * MS + a1] : (Ms[a1 * MS + b1] + Ms[b1 * MS + a1]);
      *(uint16_t*)(row + k) = pk_fp8(v0, v1);
    }
    if (t < 32) *(uint16_t*)(row + KPACK + 2 * t) = pk_fp8(-us[2 * t], -us[2 * t + 1]);
    if (t >= 32 && t < 48) *(uint16_t*)(row + KCROSS + 2 * (t - 32)) = 0;
  }
}

// ---------------- GEMM (MX-fp8): S_z[n,c] = sum_{k in slice z} Aq[n,k]*Bo[c,k]
// BM=64, BN=128, BK=128 fp8; z=2 (9/8 iters) -> 1024 blocks = 4 blocks/CU.
// Inner math: mfma_scale_f32_16x16x128_f8f6f4 with UNIT E8M0 scales (0x7F =
// 2^0) -> identical fp8 e4m3 product at ~2x rate, 1/4 the MFMA instructions.
// Lane (m=lane&15, q=lane>>4) holds k in [q*32, q*32+32) = logical 16B chunks
// {2q, 2q+1} of its row -> two swizzled ds_read_b128 per operand.
// Grid = (64 rows FAST, 8 cols, 2 z) for XCD pinning. XOR 16B-chunk swizzle.
// MFMA operands SWAPPED (bf, af): D row = c, D col = n -> 8B packed stores.
#define BM 64
#define BN 128
#define BK 128
__global__ __launch_bounds__(256) void gemm_s(const uint8_t* __restrict__ Aq,
                                              const uint8_t* __restrict__ Bo,
                                              __bf16* __restrict__ Sbase) {
  __shared__ uint8_t As[BM * BK];   // 8 KB
  __shared__ uint8_t Bs[BN * BK];   // 16 KB
  int t = threadIdx.x;
  int lane = t & 63;
  int w = t >> 6;
  int wr = w & 1;                  // row half: rows [wr*32, +32)
  int wc = w >> 1;                 // col half: cols [wc*64, +64)
  int rowBase = blockIdx.x * BM;   // row index FASTEST for XCD pinning
  int colBase = blockIdx.y * BN;
  int kb = blockIdx.z ? KSPLIT : 0;
  int ke = blockIdx.z ? KTOT : KSPLIT;
  __bf16* S = Sbase + (size_t)blockIdx.z * ((size_t)N_ * CP);

  f32_4 acc[2][4];
  for (int mi = 0; mi < 2; ++mi)
    for (int ni = 0; ni < 4; ++ni)
      acc[mi][ni] = (f32_4){0.f, 0.f, 0.f, 0.f};

  int m0 = lane & 15;
  int q = lane >> 4;           // K-quarter within MFMA: k = q*32 + [0,32)
  int sw = m0 & 7;             // swizzle key (row&7 == m0&7: 32,16 = 0 mod 8)
  int c0 = ((2 * q) ^ sw) << 4;      // physical 16B chunk of k-bytes [q*32, +16)
  int c1 = ((2 * q + 1) ^ sw) << 4;  // physical 16B chunk of k-bytes [q*32+16, +16)

  for (int k0 = kb; k0 < ke; k0 += BK) {
    __syncthreads();
    // stage A: 64 rows x 8 chunks(16B) = 512 chunks, 2 rounds
    for (int r = 0; r < 2; ++r) {
      int ch = r * 256 + t;
      int row_p = ch >> 3, qp = ch & 7;
      int q_log = qp ^ (row_p & 7);
      const uint8_t* g = Aq + (size_t)(rowBase + row_p) * KTOT + k0 + (q_log << 4);
      gl2lds16(g, As + ch * 16);
    }
    // stage B: 128 rows x 8 chunks = 1024 chunks, 4 rounds
    for (int r = 0; r < 4; ++r) {
      int ch = r * 256 + t;
      int row_p = ch >> 3, qp = ch & 7;
      int q_log = qp ^ (row_p & 7);
      const uint8_t* g = Bo + (size_t)(colBase + row_p) * KTOT + k0 + (q_log << 4);
      gl2lds16(g, Bs + ch * 16);
    }
    __syncthreads();
    i32_8 af[2], bf[4];
    for (int mi = 0; mi < 2; ++mi) {
      const uint8_t* base = &As[(wr * 32 + mi * 16 + m0) * BK];
      i32_4 lo = *(const i32_4*)(base + c0);
      i32_4 hi = *(const i32_4*)(base + c1);
      af[mi] = __builtin_shufflevector(lo, hi, 0, 1, 2, 3, 4, 5, 6, 7);
    }
    for (int ni = 0; ni < 4; ++ni) {
      const uint8_t* base = &Bs[(wc * 64 + ni * 16 + m0) * BK];
      i32_4 lo = *(const i32_4*)(base + c0);
      i32_4 hi = *(const i32_4*)(base + c1);
      bf[ni] = __builtin_shufflevector(lo, hi, 0, 1, 2, 3, 4, 5, 6, 7);
    }
    for (int mi = 0; mi < 2; ++mi)
      for (int ni = 0; ni < 4; ++ni)
        acc[mi][ni] = __builtin_amdgcn_mfma_scale_f32_16x16x128_f8f6f4(
            bf[ni], af[mi], acc[mi][ni], 0, 0,   // fmt A=fp8, B=fp8 (SWAPPED)
            0, 0x7F7F7F7F, 0, 0x7F7F7F7F);       // unit E8M0 scales (2^0)
  }

  // Swapped-D layout: row(=c) = (lane>>4)*4 + reg, col(=n) = lane&15.
  int ll = lane & 15;          // n offset
  int lh = lane >> 4;          // c quad
  for (int mi = 0; mi < 2; ++mi) {
    int n0 = rowBase + wr * 32 + mi * 16 + ll;
    for (int ni = 0; ni < 4; ++ni) {
      int cc0 = colBase + wc * 64 + ni * 16 + lh * 4;
      union { __bf16 h[4]; uint2 u; } pk;
      for (int j = 0; j < 4; ++j) pk.h[j] = (__bf16)acc[mi][ni][j];
      *(uint2*)&S[(size_t)n0 * CP + cc0] = pk.u;
    }
  }
}

// ---------------- epilogue: wave-per-row softmax + y passthrough + fused mean
__global__ __launch_bounds__(256) void epilogue(
    const __bf16* __restrict__ Sb, const float* __restrict__ y,
    const float* __restrict__ w2, const float* __restrict__ qn,
    const int* __restrict__ tgt, const float* __restrict__ ratio_p,
    float* __restrict__ nll, float* __restrict__ outy,
    float* __restrict__ out0, int* __restrict__ cnt) {
  int t = threadIdx.x, lane = t & 63, w = t >> 6;
  int n = blockIdx.x * 4 + w;
  float hr = 0.5f * (*ratio_p);
  int lbl = tgt[n];
  float q = qn[n];
  float w2k = w2[lbl];
  const bf16_8* S0 = (const bf16_8*)(Sb + (size_t)n * CP);
  const bf16_8* S1 = (const bf16_8*)(Sb + 1ull * N_ * CP + (size_t)n * CP);
  const float* yr = y + (size_t)n * C_;
  float* oy = outy + (size_t)n * C_;
  float l[16];
  float mx = -1e30f;
  for (int i = 0; i < 2; ++i) {
    int idx = i * 64 + lane;             // bf16_8 index; c = idx*8+j
    bf16_8 a0 = S0[idx], a1 = S1[idx];
    int c0 = idx * 8;
    for (int j = 0; j < 8; ++j) {
      int c = c0 + j;
      float v = -1e30f;
      if (c < C_) {
        float s = (float)a0[j] + (float)a1[j];
        v = yr[c] + (w2[c] - w2k) + hr * (s + q);
      }
      l[i * 8 + j] = v;
      mx = fmaxf(mx, v);
    }
  }
  // y passthrough (out+1 is only 4B-aligned -> scalar coalesced copy)
  for (int c = lane; c < C_; c += 64) oy[c] = yr[c];
  for (int o = 32; o; o >>= 1) mx = fmaxf(mx, __shfl_xor(mx, o));
  float se = 0.f, lt = 0.f;
  for (int i = 0; i < 2; ++i) {
    int c0 = (i * 64 + lane) * 8;
    for (int j = 0; j < 8; ++j) {
      float v = l[i * 8 + j];
      se += expf(v - mx);               // -1e30 lanes contribute exactly 0
      lt += (c0 + j == lbl) ? v : 0.f;
    }
  }
  for (int o = 32; o; o >>= 1) {
    se += __shfl_xor(se, o);
    lt += __shfl_xor(lt, o);
  }
  if (lane == 0) nll[n] = (mx + logf(se)) - lt;

  // ---- fused deterministic mean: last block to finish reduces nll ----
  __syncthreads();                      // all 4 waves' nll writes issued
  __shared__ int lastf;
  if (t == 0) {
    __threadfence();                    // make this block's nll visible device-wide
    int old = atomicAdd(cnt, 1);
    lastf = (old == (int)gridDim.x - 1);
  }
  __syncthreads();
  if (lastf) {
    __threadfence();                    // acquire: see all blocks' nll
    float s = 0.f;
    for (int i = t; i < N_; i += 256) s += nll[i];
    for (int o = 32; o; o >>= 1) s += __shfl_down(s, o);
    __shared__ float r[4];
    if ((t & 63) == 0) r[t >> 6] = s;
    __syncthreads();
    if (t == 0) out0[0] = (r[0] + r[1] + r[2] + r[3]) * (1.0f / (float)N_);
  }
}

extern "C" void kernel_launch(void* const* d_in, const int* in_sizes, int n_in,
                              void* d_out, int out_size, void* d_ws, size_t ws_size,
                              hipStream_t stream) {
  const float* W     = (const float*)d_in[0];   // (C, A)
  const float* y     = (const float*)d_in[1];   // (N, C)
  const int*   tgt   = (const int*)d_in[3];     // (N,)
  const float* ratio = (const float*)d_in[4];   // scalar
  const float* CV    = (const float*)d_in[5];   // (N, A, A)

  char* ws = (char*)d_ws;
  size_t off = 0;
  uint8_t* Aq = (uint8_t*)(ws + off); off += (size_t)N_ * KTOT;
  uint8_t* Bo = (uint8_t*)(ws + off); off += (size_t)CP * KTOT;
  __bf16* S   = (__bf16*)(ws + off);  off += 2ull * N_ * CP * sizeof(__bf16);
  float* w2   = (float*)(ws + off);   off += 4096;
  float* qn   = (float*)(ws + off);   off += (size_t)N_ * sizeof(float);
  float* nll  = (float*)(ws + off);   off += (size_t)N_ * sizeof(float);
  int*   cnt  = (int*)(ws + off);     off += 256;

  float* out = (float*)d_out;

  prep_all<<<1024 + N_, 256, 0, stream>>>(W, tgt, CV, Bo, w2, Aq, qn, cnt);
  gemm_s<<<dim3(N_ / BM, CP / BN, 2), 256, 0, stream>>>(Aq, Bo, S);
  epilogue<<<N_ / 4, 256, 0, stream>>>(S, y, w2, qn, tgt, ratio, nll, out + 1, out, cnt);
}

// Round 4
// 158.847 us; speedup vs baseline: 1.1921x; 1.1921x over previous
//
#include <hip/hip_runtime.h>
#include <hip/hip_bf16.h>
#include <stdint.h>
#include <stddef.h>

#define N_    4096
#define C_    1000
#define CP    1024
#define A_    64
#define KPACK 2080            // 64*65/2 packed upper-triangular
#define KCROSS (KPACK + 64)   // 2144 (end of live data)
#define KTOT  2176            // row length in fp8 bytes (17 x 128)
#define KSPLIT 1152           // z-slice boundary: 9 + 8 iterations of BK=128
#define MS    68              // LDS row stride (16B-aligned; mod32=4 -> 8-way max on transposed read)

typedef __bf16 bf16_8 __attribute__((ext_vector_type(8)));
typedef float  f32_4  __attribute__((ext_vector_type(4)));
typedef int    i32_4  __attribute__((ext_vector_type(4)));
typedef int    i32_8  __attribute__((ext_vector_type(8)));

__device__ __forceinline__ void gl2lds16(const void* g, void* l) {
  __builtin_amdgcn_global_load_lds(
      (const __attribute__((address_space(1))) void*)g,
      (__attribute__((address_space(3))) void*)l, 16, 0, 0);
}

// pack two floats -> two OCP e4m3 bytes (low 16 bits)
__device__ __forceinline__ uint16_t pk_fp8(float a, float b) {
  return (uint16_t)(__builtin_amdgcn_cvt_pk_fp8_f32(a, b, 0, false) & 0xffff);
}

// compile-time k -> (a<<8)|b table for packed upper-tri (a-major, b=a..63)
struct PairTab { uint16_t v[KPACK]; };
constexpr PairTab make_tab() {
  PairTab t{};
  int k = 0;
  for (int a = 0; a < 64; ++a)
    for (int b = a; b < 64; ++b) { t.v[k] = (uint16_t)((a << 8) | b); ++k; }
  return t;
}
__device__ constexpr PairTab PT = make_tab();

// ---------------- prep_all: blocks [0,1024) -> Bo + w2; [1024,5120) -> Aq + qn
__global__ __launch_bounds__(256) void prep_all(
    const float* __restrict__ W, const int* __restrict__ tgt,
    const float* __restrict__ CV, uint8_t* __restrict__ Bo,
    float* __restrict__ w2, uint8_t* __restrict__ Aq, float* __restrict__ qn) {
  __shared__ float Ms[64 * MS];
  __shared__ float up[4 * 64];
  __shared__ float wk[64];
  __shared__ float us[64];
  int t = threadIdx.x;

  if (blockIdx.x < 1024) {
    int c = blockIdx.x;
    float* ws = Ms;
    if (t < 64) {
      float w = (c < C_) ? W[c * 64 + t] : 0.f;
      ws[t] = w;
      float s = w * w;
      for (int o = 32; o; o >>= 1) s += __shfl_down(s, o);
      if (t == 0 && c < C_) w2[c] = s;
    }
    __syncthreads();
    uint8_t* row = Bo + (size_t)c * KTOT;
    for (int p = t; p < KPACK / 2; p += 256) {
      int k = 2 * p;
      uint32_t pr = *(const uint32_t*)&PT.v[k];
      int b0 = pr & 255, a0 = (pr >> 8) & 255;
      int b1 = (pr >> 16) & 255, a1 = (pr >> 24) & 255;
      *(uint16_t*)(row + k) = pk_fp8(ws[a0] * ws[b0], ws[a1] * ws[b1]);
    }
    if (t < 32) *(uint16_t*)(row + KPACK + 2 * t) = pk_fp8(ws[2 * t], ws[2 * t + 1]);
    if (t >= 32 && t < 48) *(uint16_t*)(row + KCROSS + 2 * (t - 32)) = 0;
  } else {
    int n = blockIdx.x - 1024;
    int lbl = tgt[n];
    if (t < 64) wk[t] = W[lbl * 64 + t];
    const float4* M4 = (const float4*)(CV + (size_t)n * 4096);
    for (int j = 0; j < 4; ++j) {
      int i4 = t + j * 256;
      int r = i4 >> 4, c4 = (i4 & 15) << 2;
      *(float4*)&Ms[r * MS + c4] = M4[i4];
    }
    __syncthreads();
    {
      int a = t & 63, seg = t >> 6;
      float acc = 0.f;
      for (int b = seg * 16; b < seg * 16 + 16; ++b)
        acc += (Ms[a * MS + b] + Ms[b * MS + a]) * wk[b];
      up[seg * 64 + a] = acc;
    }
    __syncthreads();
    if (t < 64) {
      float u = up[t] + up[64 + t] + up[128 + t] + up[192 + t];
      us[t] = u;
      float p = wk[t] * u;
      for (int o = 32; o; o >>= 1) p += __shfl_down(p, o);
      if (t == 0) qn[n] = 0.5f * p;
    }
    __syncthreads();
    uint8_t* row = Aq + (size_t)n * KTOT;
    for (int p = t; p < KPACK / 2; p += 256) {
      int k = 2 * p;
      uint32_t pr = *(const uint32_t*)&PT.v[k];
      int b0 = pr & 255, a0 = (pr >> 8) & 255;
      int b1 = (pr >> 16) & 255, a1 = (pr >> 24) & 255;
      float v0 = (a0 == b0) ? Ms[a0 * MS + a0] : (Ms[a0 * MS + b0] + Ms[b0 * MS + a0]);
      float v1 = (a1 == b1) ? Ms[a1 * MS + a1] : (Ms[a1 * MS + b1] + Ms[b1 * MS + a1]);
      *(uint16_t*)(row + k) = pk_fp8(v0, v1);
    }
    if (t < 32) *(uint16_t*)(row + KPACK + 2 * t) = pk_fp8(-us[2 * t], -us[2 * t + 1]);
    if (t >= 32 && t < 48) *(uint16_t*)(row + KCROSS + 2 * (t - 32)) = 0;
  }
}

// ---------------- GEMM (MX-fp8): S_z[n,c] = sum_{k in slice z} Aq[n,k]*Bo[c,k]
// BM=64, BN=128, BK=128 fp8; z=2 (9/8 iters) -> 1024 blocks = 4 blocks/CU.
// Inner math: mfma_scale_f32_16x16x128_f8f6f4 with UNIT E8M0 scales (0x7F =
// 2^0) -> identical fp8 e4m3 product at ~2x rate, 1/4 the MFMA instructions.
// Lane (m=lane&15, q=lane>>4) holds k in [q*32, q*32+32) = logical 16B chunks
// {2q, 2q+1} of its row -> two swizzled ds_read_b128 per operand.
// Grid = (64 rows FAST, 8 cols, 2 z) for XCD pinning. XOR 16B-chunk swizzle.
// MFMA operands SWAPPED (bf, af): D row = c, D col = n -> 8B packed stores.
#define BM 64
#define BN 128
#define BK 128
__global__ __launch_bounds__(256) void gemm_s(const uint8_t* __restrict__ Aq,
                                              const uint8_t* __restrict__ Bo,
                                              __bf16* __restrict__ Sbase) {
  __shared__ uint8_t As[BM * BK];   // 8 KB
  __shared__ uint8_t Bs[BN * BK];   // 16 KB
  int t = threadIdx.x;
  int lane = t & 63;
  int w = t >> 6;
  int wr = w & 1;                  // row half: rows [wr*32, +32)
  int wc = w >> 1;                 // col half: cols [wc*64, +64)
  int rowBase = blockIdx.x * BM;   // row index FASTEST for XCD pinning
  int colBase = blockIdx.y * BN;
  int kb = blockIdx.z ? KSPLIT : 0;
  int ke = blockIdx.z ? KTOT : KSPLIT;
  __bf16* S = Sbase + (size_t)blockIdx.z * ((size_t)N_ * CP);

  f32_4 acc[2][4];
  for (int mi = 0; mi < 2; ++mi)
    for (int ni = 0; ni < 4; ++ni)
      acc[mi][ni] = (f32_4){0.f, 0.f, 0.f, 0.f};

  int m0 = lane & 15;
  int q = lane >> 4;           // K-quarter within MFMA: k = q*32 + [0,32)
  int sw = m0 & 7;             // swizzle key (row&7 == m0&7: 32,16 = 0 mod 8)
  int c0 = ((2 * q) ^ sw) << 4;      // physical 16B chunk of k-bytes [q*32, +16)
  int c1 = ((2 * q + 1) ^ sw) << 4;  // physical 16B chunk of k-bytes [q*32+16, +16)

  for (int k0 = kb; k0 < ke; k0 += BK) {
    __syncthreads();
    // stage A: 64 rows x 8 chunks(16B) = 512 chunks, 2 rounds
    for (int r = 0; r < 2; ++r) {
      int ch = r * 256 + t;
      int row_p = ch >> 3, qp = ch & 7;
      int q_log = qp ^ (row_p & 7);
      const uint8_t* g = Aq + (size_t)(rowBase + row_p) * KTOT + k0 + (q_log << 4);
      gl2lds16(g, As + ch * 16);
    }
    // stage B: 128 rows x 8 chunks = 1024 chunks, 4 rounds
    for (int r = 0; r < 4; ++r) {
      int ch = r * 256 + t;
      int row_p = ch >> 3, qp = ch & 7;
      int q_log = qp ^ (row_p & 7);
      const uint8_t* g = Bo + (size_t)(colBase + row_p) * KTOT + k0 + (q_log << 4);
      gl2lds16(g, Bs + ch * 16);
    }
    __syncthreads();
    i32_8 af[2], bf[4];
    for (int mi = 0; mi < 2; ++mi) {
      const uint8_t* base = &As[(wr * 32 + mi * 16 + m0) * BK];
      i32_4 lo = *(const i32_4*)(base + c0);
      i32_4 hi = *(const i32_4*)(base + c1);
      af[mi] = __builtin_shufflevector(lo, hi, 0, 1, 2, 3, 4, 5, 6, 7);
    }
    for (int ni = 0; ni < 4; ++ni) {
      const uint8_t* base = &Bs[(wc * 64 + ni * 16 + m0) * BK];
      i32_4 lo = *(const i32_4*)(base + c0);
      i32_4 hi = *(const i32_4*)(base + c1);
      bf[ni] = __builtin_shufflevector(lo, hi, 0, 1, 2, 3, 4, 5, 6, 7);
    }
    for (int mi = 0; mi < 2; ++mi)
      for (int ni = 0; ni < 4; ++ni)
        acc[mi][ni] = __builtin_amdgcn_mfma_scale_f32_16x16x128_f8f6f4(
            bf[ni], af[mi], acc[mi][ni], 0, 0,   // fmt A=fp8, B=fp8 (SWAPPED)
            0, 0x7F7F7F7F, 0, 0x7F7F7F7F);       // unit E8M0 scales (2^0)
  }

  // Swapped-D layout: row(=c) = (lane>>4)*4 + reg, col(=n) = lane&15.
  int ll = lane & 15;          // n offset
  int lh = lane >> 4;          // c quad
  for (int mi = 0; mi < 2; ++mi) {
    int n0 = rowBase + wr * 32 + mi * 16 + ll;
    for (int ni = 0; ni < 4; ++ni) {
      int cc0 = colBase + wc * 64 + ni * 16 + lh * 4;
      union { __bf16 h[4]; uint2 u; } pk;
      for (int j = 0; j < 4; ++j) pk.h[j] = (__bf16)acc[mi][ni][j];
      *(uint2*)&S[(size_t)n0 * CP + cc0] = pk.u;
    }
  }
}

// ---------------- epilogue: wave-per-row softmax + y passthrough ----------------
// Lane layout matches S fragments: lane covers c = lane*8..+7 (lo) and
// 512+lane*8..+7 (hi, valid iff lane<61). y and w2 rows are 16B-aligned
// (4000%16==0) -> 4 independent float4 loads each, issued up-front with the
// 4 bf16x8 S loads: 12 independent vector loads, no scattered scalars.
__global__ __launch_bounds__(256) void epilogue(
    const __bf16* __restrict__ Sb, const float* __restrict__ y,
    const float* __restrict__ w2, const float* __restrict__ qn,
    const int* __restrict__ tgt, const float* __restrict__ ratio_p,
    float* __restrict__ nll, float* __restrict__ outy) {
  int t = threadIdx.x, lane = t & 63, w = t >> 6;
  int n = blockIdx.x * 4 + w;
  float hr = 0.5f * (*ratio_p);
  int lbl = tgt[n];
  float q = qn[n];
  float w2k = w2[lbl];
  const bf16_8* S0 = (const bf16_8*)(Sb + (size_t)n * CP);
  const bf16_8* S1 = (const bf16_8*)(Sb + 1ull * N_ * CP + (size_t)n * CP);
  const float* yr = y + (size_t)n * C_;
  float* oy = outy + (size_t)n * C_;

  bf16_8 a00 = S0[lane], a01 = S0[64 + lane];
  bf16_8 a10 = S1[lane], a11 = S1[64 + lane];
  f32_4 y0a = *(const f32_4*)(yr + lane * 8);
  f32_4 y0b = *(const f32_4*)(yr + lane * 8 + 4);
  f32_4 w0a = *(const f32_4*)(w2 + lane * 8);
  f32_4 w0b = *(const f32_4*)(w2 + lane * 8 + 4);
  f32_4 y1a = {0.f, 0.f, 0.f, 0.f}, y1b = y1a, w1a = y1a, w1b = y1a;
  bool hiv = (lane < 61);              // hi half valid: 512+lane*8+7 <= 999
  if (hiv) {
    y1a = *(const f32_4*)(yr + 512 + lane * 8);
    y1b = *(const f32_4*)(yr + 512 + lane * 8 + 4);
    w1a = *(const f32_4*)(w2 + 512 + lane * 8);
    w1b = *(const f32_4*)(w2 + 512 + lane * 8 + 4);
  }

  float l[16];
  float mx = -1e30f, lt = 0.f;
#pragma unroll
  for (int j = 0; j < 8; ++j) {
    float s = (float)a00[j] + (float)a10[j];
    float yj = (j < 4) ? y0a[j] : y0b[j - 4];
    float wj = (j < 4) ? w0a[j] : w0b[j - 4];
    float v = yj + (wj - w2k) + hr * (s + q);
    l[j] = v;
    mx = fmaxf(mx, v);
    lt += (lane * 8 + j == lbl) ? v : 0.f;
  }
#pragma unroll
  for (int j = 0; j < 8; ++j) {
    float v = -1e30f;
    if (hiv) {
      float s = (float)a01[j] + (float)a11[j];
      float yj = (j < 4) ? y1a[j] : y1b[j - 4];
      float wj = (j < 4) ? w1a[j] : w1b[j - 4];
      v = yj + (wj - w2k) + hr * (s + q);
      lt += (512 + lane * 8 + j == lbl) ? v : 0.f;
    }
    l[8 + j] = v;
    mx = fmaxf(mx, v);
  }
  // y passthrough (out+1 only 4B-aligned -> scalar coalesced; yr is L1-hot)
  for (int c = lane; c < C_; c += 64) oy[c] = yr[c];
  for (int o = 32; o; o >>= 1) mx = fmaxf(mx, __shfl_xor(mx, o));
  float se = 0.f;
#pragma unroll
  for (int i = 0; i < 16; ++i) se += expf(l[i] - mx);   // masked lanes -> 0
  for (int o = 32; o; o >>= 1) {
    se += __shfl_xor(se, o);
    lt += __shfl_xor(lt, o);
  }
  if (lane == 0) nll[n] = (mx + logf(se)) - lt;
}

// ---------------- final mean (single block, no atomics) ----------------
__global__ void reduce_loss(const float* __restrict__ nll, float* __restrict__ out) {
  int t = threadIdx.x;  // 256
  float s = 0.f;
  for (int i = t; i < N_; i += 256) s += nll[i];
  for (int o = 32; o; o >>= 1) s += __shfl_down(s, o);
  __shared__ float r[4];
  if ((t & 63) == 0) r[t >> 6] = s;
  __syncthreads();
  if (t == 0) out[0] = (r[0] + r[1] + r[2] + r[3]) * (1.0f / (float)N_);
}

extern "C" void kernel_launch(void* const* d_in, const int* in_sizes, int n_in,
                              void* d_out, int out_size, void* d_ws, size_t ws_size,
                              hipStream_t stream) {
  const float* W     = (const float*)d_in[0];   // (C, A)
  const float* y     = (const float*)d_in[1];   // (N, C)
  const int*   tgt   = (const int*)d_in[3];     // (N,)
  const float* ratio = (const float*)d_in[4];   // scalar
  const float* CV    = (const float*)d_in[5];   // (N, A, A)

  char* ws = (char*)d_ws;
  size_t off = 0;
  uint8_t* Aq = (uint8_t*)(ws + off); off += (size_t)N_ * KTOT;
  uint8_t* Bo = (uint8_t*)(ws + off); off += (size_t)CP * KTOT;
  __bf16* S   = (__bf16*)(ws + off);  off += 2ull * N_ * CP * sizeof(__bf16);
  float* w2   = (float*)(ws + off);   off += 4096;
  float* qn   = (float*)(ws + off);   off += (size_t)N_ * sizeof(float);
  float* nll  = (float*)(ws + off);   off += (size_t)N_ * sizeof(float);

  float* out = (float*)d_out;

  prep_all<<<1024 + N_, 256, 0, stream>>>(W, tgt, CV, Bo, w2, Aq, qn);
  gemm_s<<<dim3(N_ / BM, CP / BN, 2), 256, 0, stream>>>(Aq, Bo, S);
  epilogue<<<N_ / 4, 256, 0, stream>>>(S, y, w2, qn, tgt, ratio, nll, out + 1);
  reduce_loss<<<1, 256, 0, stream>>>(nll, out);
}

// Round 5
// 158.272 us; speedup vs baseline: 1.1964x; 1.0036x over previous
//
#include <hip/hip_runtime.h>
#include <hip/hip_bf16.h>
#include <stdint.h>
#include <stddef.h>

#define N_    4096
#define C_    1000
#define CP    1024
#define A_    64
#define KPACK 2080            // 64*65/2 packed upper-triangular
#define KCROSS (KPACK + 64)   // 2144 (end of live data)
#define KTOT  2176            // row length in fp8 bytes (17 x 128)
#define KSPLIT 1152           // z-slice boundary: 9 + 8 iterations of BK=128
#define MS    65              // LDS row stride: 65%32==1 -> bank=(a+b)%32, BOTH read orientations conflict-free

typedef __bf16 bf16_8 __attribute__((ext_vector_type(8)));
typedef float  f32_4  __attribute__((ext_vector_type(4)));
typedef int    i32_4  __attribute__((ext_vector_type(4)));
typedef int    i32_8  __attribute__((ext_vector_type(8)));

__device__ __forceinline__ void gl2lds16(const void* g, void* l) {
  __builtin_amdgcn_global_load_lds(
      (const __attribute__((address_space(1))) void*)g,
      (__attribute__((address_space(3))) void*)l, 16, 0, 0);
}

// pack two floats -> two OCP e4m3 bytes (low 16 bits)
__device__ __forceinline__ uint16_t pk_fp8(float a, float b) {
  return (uint16_t)(__builtin_amdgcn_cvt_pk_fp8_f32(a, b, 0, false) & 0xffff);
}

// compile-time k -> (a<<8)|b table for packed upper-tri (a-major, b=a..63)
struct PairTab { uint16_t v[KPACK]; };
constexpr PairTab make_tab() {
  PairTab t{};
  int k = 0;
  for (int a = 0; a < 64; ++a)
    for (int b = a; b < 64; ++b) { t.v[k] = (uint16_t)((a << 8) | b); ++k; }
  return t;
}
__device__ constexpr PairTab PT = make_tab();

// ---------------- prep_all: blocks [0,1024) -> Bo + w2; [1024,5120) -> Aq + qn
__global__ __launch_bounds__(256) void prep_all(
    const float* __restrict__ W, const int* __restrict__ tgt,
    const float* __restrict__ CV, uint8_t* __restrict__ Bo,
    float* __restrict__ w2, uint8_t* __restrict__ Aq, float* __restrict__ qn) {
  __shared__ float Ms[64 * MS];
  __shared__ float up[4 * 64];
  __shared__ float wk[64];
  __shared__ float us[64];
  int t = threadIdx.x;

  if (blockIdx.x < 1024) {
    int c = blockIdx.x;
    float* ws = Ms;
    if (t < 64) {
      float w = (c < C_) ? W[c * 64 + t] : 0.f;
      ws[t] = w;
      float s = w * w;
      for (int o = 32; o; o >>= 1) s += __shfl_down(s, o);
      if (t == 0 && c < C_) w2[c] = s;
    }
    __syncthreads();
    uint8_t* row = Bo + (size_t)c * KTOT;
    for (int p = t; p < KPACK / 2; p += 256) {
      int k = 2 * p;
      uint32_t pr = *(const uint32_t*)&PT.v[k];
      int b0 = pr & 255, a0 = (pr >> 8) & 255;
      int b1 = (pr >> 16) & 255, a1 = (pr >> 24) & 255;
      *(uint16_t*)(row + k) = pk_fp8(ws[a0] * ws[b0], ws[a1] * ws[b1]);
    }
    if (t < 32) *(uint16_t*)(row + KPACK + 2 * t) = pk_fp8(ws[2 * t], ws[2 * t + 1]);
    if (t >= 32 && t < 48) *(uint16_t*)(row + KCROSS + 2 * (t - 32)) = 0;
  } else {
    int n = blockIdx.x - 1024;
    int lbl = tgt[n];
    if (t < 64) wk[t] = W[lbl * 64 + t];
    // float4 global loads; scalar LDS writes (MS=65 rows are not 16B-aligned)
    const float4* M4 = (const float4*)(CV + (size_t)n * 4096);
    for (int j = 0; j < 4; ++j) {
      int i4 = t + j * 256;
      float4 v = M4[i4];
      int r = i4 >> 4, c4 = (i4 & 15) << 2;
      float* d = &Ms[r * MS + c4];
      d[0] = v.x; d[1] = v.y; d[2] = v.z; d[3] = v.w;
    }
    __syncthreads();
    {
      int a = t & 63, seg = t >> 6;
      float acc = 0.f;
      for (int b = seg * 16; b < seg * 16 + 16; ++b)
        acc += (Ms[a * MS + b] + Ms[b * MS + a]) * wk[b];
      up[seg * 64 + a] = acc;
    }
    __syncthreads();
    if (t < 64) {
      float u = up[t] + up[64 + t] + up[128 + t] + up[192 + t];
      us[t] = u;
      float p = wk[t] * u;
      for (int o = 32; o; o >>= 1) p += __shfl_down(p, o);
      if (t == 0) qn[n] = 0.5f * p;
    }
    __syncthreads();
    uint8_t* row = Aq + (size_t)n * KTOT;
    for (int p = t; p < KPACK / 2; p += 256) {
      int k = 2 * p;
      uint32_t pr = *(const uint32_t*)&PT.v[k];
      int b0 = pr & 255, a0 = (pr >> 8) & 255;
      int b1 = (pr >> 16) & 255, a1 = (pr >> 24) & 255;
      float v0 = (a0 == b0) ? Ms[a0 * MS + a0] : (Ms[a0 * MS + b0] + Ms[b0 * MS + a0]);
      float v1 = (a1 == b1) ? Ms[a1 * MS + a1] : (Ms[a1 * MS + b1] + Ms[b1 * MS + a1]);
      *(uint16_t*)(row + k) = pk_fp8(v0, v1);
    }
    if (t < 32) *(uint16_t*)(row + KPACK + 2 * t) = pk_fp8(-us[2 * t], -us[2 * t + 1]);
    if (t >= 32 && t < 48) *(uint16_t*)(row + KCROSS + 2 * (t - 32)) = 0;
  }
}

// ---------------- GEMM (MX-fp8): S_z[n,c] = sum_{k in slice z} Aq[n,k]*Bo[c,k]
// BM=128, BN=128, BK=128 fp8; z=2 -> 512 blocks = 2/CU.  L2 traffic:
// A = 8.9MB x 8 colblocks + B = 2.2MB x 32 rowblocks = 142 MB (was 213 at BM=64).
// Inner math: mfma_scale_f32_16x16x128_f8f6f4 with UNIT E8M0 scales (0x7F=2^0).
// Lane (m=lane&15, q=lane>>4) holds k in [q*32,+32) = logical 16B chunks
// {2q,2q+1} -> two swizzled ds_read_b128 per operand fragment.
// 4 waves = 2x2 of 64x64 wave-tiles. XOR 16B-chunk swizzle (row&7).
// MFMA operands SWAPPED (bf, af): D row = c, D col = n -> 8B packed stores.
#define BM 128
#define BN 128
#define BK 128
__global__ __launch_bounds__(256) void gemm_s(const uint8_t* __restrict__ Aq,
                                              const uint8_t* __restrict__ Bo,
                                              __bf16* __restrict__ Sbase) {
  __shared__ uint8_t As[BM * BK];   // 16 KB
  __shared__ uint8_t Bs[BN * BK];   // 16 KB
  int t = threadIdx.x;
  int lane = t & 63;
  int w = t >> 6;
  int wr = w & 1;                  // row half: rows [wr*64, +64)
  int wc = w >> 1;                 // col half: cols [wc*64, +64)
  int rowBase = blockIdx.x * BM;   // row index FASTEST for XCD pinning
  int colBase = blockIdx.y * BN;
  int kb = blockIdx.z ? KSPLIT : 0;
  int ke = blockIdx.z ? KTOT : KSPLIT;
  __bf16* S = Sbase + (size_t)blockIdx.z * ((size_t)N_ * CP);

  f32_4 acc[4][4];
  for (int mi = 0; mi < 4; ++mi)
    for (int ni = 0; ni < 4; ++ni)
      acc[mi][ni] = (f32_4){0.f, 0.f, 0.f, 0.f};

  int m0 = lane & 15;
  int q = lane >> 4;           // K-quarter within MFMA: k = q*32 + [0,32)
  int sw = m0 & 7;             // swizzle key (row&7 == m0&7: 64,16 = 0 mod 8)
  int c0 = ((2 * q) ^ sw) << 4;      // physical 16B chunk of k-bytes [q*32, +16)
  int c1 = ((2 * q + 1) ^ sw) << 4;  // physical 16B chunk of k-bytes [q*32+16, +16)

  for (int k0 = kb; k0 < ke; k0 += BK) {
    __syncthreads();
    // stage A: 128 rows x 8 chunks(16B) = 1024 chunks, 4 rounds
    for (int r = 0; r < 4; ++r) {
      int ch = r * 256 + t;
      int row_p = ch >> 3, qp = ch & 7;
      int q_log = qp ^ (row_p & 7);
      const uint8_t* g = Aq + (size_t)(rowBase + row_p) * KTOT + k0 + (q_log << 4);
      gl2lds16(g, As + ch * 16);
    }
    // stage B: 128 rows x 8 chunks = 1024 chunks, 4 rounds
    for (int r = 0; r < 4; ++r) {
      int ch = r * 256 + t;
      int row_p = ch >> 3, qp = ch & 7;
      int q_log = qp ^ (row_p & 7);
      const uint8_t* g = Bo + (size_t)(colBase + row_p) * KTOT + k0 + (q_log << 4);
      gl2lds16(g, Bs + ch * 16);
    }
    __syncthreads();
    i32_8 af[4], bf[4];
    for (int mi = 0; mi < 4; ++mi) {
      const uint8_t* base = &As[(wr * 64 + mi * 16 + m0) * BK];
      i32_4 lo = *(const i32_4*)(base + c0);
      i32_4 hi = *(const i32_4*)(base + c1);
      af[mi] = __builtin_shufflevector(lo, hi, 0, 1, 2, 3, 4, 5, 6, 7);
    }
    for (int ni = 0; ni < 4; ++ni) {
      const uint8_t* base = &Bs[(wc * 64 + ni * 16 + m0) * BK];
      i32_4 lo = *(const i32_4*)(base + c0);
      i32_4 hi = *(const i32_4*)(base + c1);
      bf[ni] = __builtin_shufflevector(lo, hi, 0, 1, 2, 3, 4, 5, 6, 7);
    }
    for (int mi = 0; mi < 4; ++mi)
      for (int ni = 0; ni < 4; ++ni)
        acc[mi][ni] = __builtin_amdgcn_mfma_scale_f32_16x16x128_f8f6f4(
            bf[ni], af[mi], acc[mi][ni], 0, 0,   // fmt A=fp8, B=fp8 (SWAPPED)
            0, 0x7F7F7F7F, 0, 0x7F7F7F7F);       // unit E8M0 scales (2^0)
  }

  // Swapped-D layout: row(=c) = (lane>>4)*4 + reg, col(=n) = lane&15.
  int ll = lane & 15;          // n offset
  int lh = lane >> 4;          // c quad
  for (int mi = 0; mi < 4; ++mi) {
    int n0 = rowBase + wr * 64 + mi * 16 + ll;
    for (int ni = 0; ni < 4; ++ni) {
      int cc0 = colBase + wc * 64 + ni * 16 + lh * 4;
      union { __bf16 h[4]; uint2 u; } pk;
      for (int j = 0; j < 4; ++j) pk.h[j] = (__bf16)acc[mi][ni][j];
      *(uint2*)&S[(size_t)n0 * CP + cc0] = pk.u;
    }
  }
}

// ---------------- epilogue: wave-per-row softmax + y passthrough ----------------
// Lane layout matches S fragments: lane covers c = lane*8..+7 (lo) and
// 512+lane*8..+7 (hi, valid iff lane<61). y and w2 rows are 16B-aligned
// (4000%16==0) -> 4 independent float4 loads each, issued up-front with the
// 4 bf16x8 S loads: 12 independent vector loads, no scattered scalars.
__global__ __launch_bounds__(256) void epilogue(
    const __bf16* __restrict__ Sb, const float* __restrict__ y,
    const float* __restrict__ w2, const float* __restrict__ qn,
    const int* __restrict__ tgt, const float* __restrict__ ratio_p,
    float* __restrict__ nll, float* __restrict__ outy) {
  int t = threadIdx.x, lane = t & 63, w = t >> 6;
  int n = blockIdx.x * 4 + w;
  float hr = 0.5f * (*ratio_p);
  int lbl = tgt[n];
  float q = qn[n];
  float w2k = w2[lbl];
  const bf16_8* S0 = (const bf16_8*)(Sb + (size_t)n * CP);
  const bf16_8* S1 = (const bf16_8*)(Sb + 1ull * N_ * CP + (size_t)n * CP);
  const float* yr = y + (size_t)n * C_;
  float* oy = outy + (size_t)n * C_;

  bf16_8 a00 = S0[lane], a01 = S0[64 + lane];
  bf16_8 a10 = S1[lane], a11 = S1[64 + lane];
  f32_4 y0a = *(const f32_4*)(yr + lane * 8);
  f32_4 y0b = *(const f32_4*)(yr + lane * 8 + 4);
  f32_4 w0a = *(const f32_4*)(w2 + lane * 8);
  f32_4 w0b = *(const f32_4*)(w2 + lane * 8 + 4);
  f32_4 y1a = {0.f, 0.f, 0.f, 0.f}, y1b = y1a, w1a = y1a, w1b = y1a;
  bool hiv = (lane < 61);              // hi half valid: 512+lane*8+7 <= 999
  if (hiv) {
    y1a = *(const f32_4*)(yr + 512 + lane * 8);
    y1b = *(const f32_4*)(yr + 512 + lane * 8 + 4);
    w1a = *(const f32_4*)(w2 + 512 + lane * 8);
    w1b = *(const f32_4*)(w2 + 512 + lane * 8 + 4);
  }

  float l[16];
  float mx = -1e30f, lt = 0.f;
#pragma unroll
  for (int j = 0; j < 8; ++j) {
    float s = (float)a00[j] + (float)a10[j];
    float yj = (j < 4) ? y0a[j] : y0b[j - 4];
    float wj = (j < 4) ? w0a[j] : w0b[j - 4];
    float v = yj + (wj - w2k) + hr * (s + q);
    l[j] = v;
    mx = fmaxf(mx, v);
    lt += (lane * 8 + j == lbl) ? v : 0.f;
  }
#pragma unroll
  for (int j = 0; j < 8; ++j) {
    float v = -1e30f;
    if (hiv) {
      float s = (float)a01[j] + (float)a11[j];
      float yj = (j < 4) ? y1a[j] : y1b[j - 4];
      float wj = (j < 4) ? w1a[j] : w1b[j - 4];
      v = yj + (wj - w2k) + hr * (s + q);
      lt += (512 + lane * 8 + j == lbl) ? v : 0.f;
    }
    l[8 + j] = v;
    mx = fmaxf(mx, v);
  }
  // y passthrough (out+1 only 4B-aligned -> scalar coalesced; yr is L1-hot)
  for (int c = lane; c < C_; c += 64) oy[c] = yr[c];
  for (int o = 32; o; o >>= 1) mx = fmaxf(mx, __shfl_xor(mx, o));
  float se = 0.f;
#pragma unroll
  for (int i = 0; i < 16; ++i) se += expf(l[i] - mx);   // masked lanes -> 0
  for (int o = 32; o; o >>= 1) {
    se += __shfl_xor(se, o);
    lt += __shfl_xor(lt, o);
  }
  if (lane == 0) nll[n] = (mx + logf(se)) - lt;
}

// ---------------- final mean (single block, no atomics) ----------------
__global__ void reduce_loss(const float* __restrict__ nll, float* __restrict__ out) {
  int t = threadIdx.x;  // 256
  float s = 0.f;
  for (int i = t; i < N_; i += 256) s += nll[i];
  for (int o = 32; o; o >>= 1) s += __shfl_down(s, o);
  __shared__ float r[4];
  if ((t & 63) == 0) r[t >> 6] = s;
  __syncthreads();
  if (t == 0) out[0] = (r[0] + r[1] + r[2] + r[3]) * (1.0f / (float)N_);
}

extern "C" void kernel_launch(void* const* d_in, const int* in_sizes, int n_in,
                              void* d_out, int out_size, void* d_ws, size_t ws_size,
                              hipStream_t stream) {
  const float* W     = (const float*)d_in[0];   // (C, A)
  const float* y     = (const float*)d_in[1];   // (N, C)
  const int*   tgt   = (const int*)d_in[3];     // (N,)
  const float* ratio = (const float*)d_in[4];   // scalar
  const float* CV    = (const float*)d_in[5];   // (N, A, A)

  char* ws = (char*)d_ws;
  size_t off = 0;
  uint8_t* Aq = (uint8_t*)(ws + off); off += (size_t)N_ * KTOT;
  uint8_t* Bo = (uint8_t*)(ws + off); off += (size_t)CP * KTOT;
  __bf16* S   = (__bf16*)(ws + off);  off += 2ull * N_ * CP * sizeof(__bf16);
  float* w2   = (float*)(ws + off);   off += 4096;
  float* qn   = (float*)(ws + off);   off += (size_t)N_ * sizeof(float);
  float* nll  = (float*)(ws + off);   off += (size_t)N_ * sizeof(float);

  float* out = (float*)d_out;

  prep_all<<<1024 + N_, 256, 0, stream>>>(W, tgt, CV, Bo, w2, Aq, qn);
  gemm_s<<<dim3(N_ / BM, CP / BN, 2), 256, 0, stream>>>(Aq, Bo, S);
  epilogue<<<N_ / 4, 256, 0, stream>>>(S, y, w2, qn, tgt, ratio, nll, out + 1);
  reduce_loss<<<1, 256, 0, stream>>>(nll, out);
}